// Round 1
// baseline (858.639 us; speedup 1.0000x reference)
//
#include <hip/hip_runtime.h>
#include <math.h>

// Problem constants
//   x:      (4,16,256,128) f32  -> rows = 16384, C = 128
//   w_qkv:  (128, 384) f32      -> only k (cols 128..255) and v (256..383) used
//   w_out:  (128, 128) f32
//   b_out:  (128,) f32
//   out:    (4,16,256,128) f32
//
// Derived mapping of the reference's reshape (b,h,w,128)->(b,32,4096,4):
//   j = pos>>7, d/e = (pos&127)*32 + (c>>2), a = c&3
// Per (b,a) pair: flash attention, seq 4096, dim 32:
//   Q[d][j] = 10 * l2norm4(k)[...],  M[e][j] = v[...]  (M is both K and V)
//   out_pre[b][d][n2*4+a] = softmax_e(Q M^T)[d,:] . M[:,n2]
// Final: y = out_pre @ w_out + b_out.

#define NPAIR 16
#define SEQ   4096

// ---------------------------------------------------------------------------
// Kernel 1: k/v GEMM (skip unused q) + group-of-4 L2 norm on k + scatter
// ---------------------------------------------------------------------------
__global__ __launch_bounds__(256) void kv_kernel(const float* __restrict__ x,
                                                 const float* __restrict__ wqkv,
                                                 float* __restrict__ Qm,
                                                 float* __restrict__ MmT) {
    __shared__ __align__(16) float xs[16][128];
    const int r0 = blockIdx.x * 16;          // 1024 blocks x 16 rows
    const int t  = threadIdx.x;

    // load 16 x-rows (2048 floats = 512 float4)
    {
        const float4* xv = (const float4*)(x + (size_t)r0 * 128);
        float4* xsv = (float4*)&xs[0][0];
        xsv[t]       = xv[t];
        xsv[t + 256] = xv[t + 256];
    }
    __syncthreads();

    const int c    = t & 127;
    const int half = t >> 7;                 // 0: k, 1: v
    const int off  = 128 + half * 128 + c;

    float acc[16];
#pragma unroll
    for (int p = 0; p < 16; ++p) acc[p] = 0.f;

    for (int i = 0; i < 128; i += 4) {
        float w0 = wqkv[(i + 0) * 384 + off];
        float w1 = wqkv[(i + 1) * 384 + off];
        float w2 = wqkv[(i + 2) * 384 + off];
        float w3 = wqkv[(i + 3) * 384 + off];
#pragma unroll
        for (int p = 0; p < 16; ++p) {
            float4 xp = *(const float4*)&xs[p][i];
            acc[p] = fmaf(xp.x, w0, acc[p]);
            acc[p] = fmaf(xp.y, w1, acc[p]);
            acc[p] = fmaf(xp.z, w2, acc[p]);
            acc[p] = fmaf(xp.w, w3, acc[p]);
        }
    }

    const int a  = c & 3;
    const int cg = c >> 2;

    if (half == 0) {
        // k: L2-normalize each group of 4 consecutive channels, fold SCALE=10
#pragma unroll
        for (int p = 0; p < 16; ++p) {
            float v = acc[p];
            float s = v * v;
            s += __shfl_xor(s, 1);
            s += __shfl_xor(s, 2);
            float n  = fmaxf(sqrtf(s), 1e-12f);
            float kn = v / n * 10.0f;
            int row  = r0 + p;
            int b    = row >> 12;
            int pos  = row & 4095;
            int j    = pos >> 7;
            int d    = ((pos & 127) << 5) + cg;
            int pair = (b << 2) + a;
            Qm[((size_t)(pair * SEQ + d)) * 32 + j] = kn;
        }
    } else {
        // v -> MmT[pair][j][e]
#pragma unroll
        for (int p = 0; p < 16; ++p) {
            int row  = r0 + p;
            int b    = row >> 12;
            int pos  = row & 4095;
            int j    = pos >> 7;
            int e    = ((pos & 127) << 5) + cg;
            int pair = (b << 2) + a;
            MmT[((size_t)(pair * 32 + j)) * SEQ + e] = acc[p];
        }
    }
}

// ---------------------------------------------------------------------------
// Kernel 2: flash attention per (pair, 64-row d-tile); fp32 vector ALU
// ---------------------------------------------------------------------------
__global__ __launch_bounds__(256) void attn_kernel(const float* __restrict__ Qm,
                                                   const float* __restrict__ MmT,
                                                   float* __restrict__ out_pre) {
    __shared__ __align__(16) float Qt[64][36];   // Q rows (padded)
    __shared__ __align__(16) float Mt[32][68];   // M^T tile: [j][e-local]
    __shared__ __align__(16) float Pt[64][68];   // P tile (padded)

    const int blk  = blockIdx.x;                 // 16 pairs * 64 d-tiles
    const int pair = blk >> 6;
    const int d0   = (blk & 63) * 64;
    const int t    = threadIdx.x;
    const int tx   = t & 15;
    const int ty   = t >> 4;
    const int ty4  = ty * 4;
    const int tx4  = tx * 4;
    const int tx2  = tx * 2;

    // load Q tile: 64 rows x 32 (512 float4, 2 per thread)
    {
        const float4* qsrc = (const float4*)(Qm + ((size_t)(pair * SEQ + d0)) * 32);
#pragma unroll
        for (int u = 0; u < 2; ++u) {
            int idx = t * 2 + u;                 // 0..511
            int r   = idx >> 3;                  // 8 float4 per row
            int jc  = (idx & 7) * 4;
            *(float4*)&Qt[r][jc] = qsrc[idx];
        }
    }

    float m_r[4], l_r[4], O[4][2];
#pragma unroll
    for (int rr = 0; rr < 4; ++rr) {
        m_r[rr] = -1e30f; l_r[rr] = 0.f; O[rr][0] = 0.f; O[rr][1] = 0.f;
    }

    const float* msrc = MmT + (size_t)pair * 32 * SEQ;

    for (int e0 = 0; e0 < SEQ; e0 += 64) {
        __syncthreads();                         // prior Mt/Pt reads done
        // load M^T tile: 32 rows x 64 (512 float4)
#pragma unroll
        for (int u = 0; u < 2; ++u) {
            int idx = t * 2 + u;
            int j   = idx >> 4;                  // 16 float4 per row
            int cc4 = (idx & 15) * 4;
            *(float4*)&Mt[j][cc4] = *(const float4*)(msrc + (size_t)j * SEQ + e0 + cc4);
        }
        __syncthreads();

        // S = Q . Mt^T  (4x4 per thread: rows ty4+rr, cols tx4+cc)
        float S[4][4];
#pragma unroll
        for (int rr = 0; rr < 4; ++rr)
#pragma unroll
            for (int cc = 0; cc < 4; ++cc) S[rr][cc] = 0.f;

        for (int j = 0; j < 32; j += 4) {
            float qv[4][4], mv[4][4];
#pragma unroll
            for (int rr = 0; rr < 4; ++rr)
                *(float4*)qv[rr] = *(const float4*)&Qt[ty4 + rr][j];
#pragma unroll
            for (int jj = 0; jj < 4; ++jj)
                *(float4*)mv[jj] = *(const float4*)&Mt[j + jj][tx4];
#pragma unroll
            for (int rr = 0; rr < 4; ++rr)
#pragma unroll
                for (int cc = 0; cc < 4; ++cc) {
                    float s = S[rr][cc];
                    s = fmaf(qv[rr][0], mv[0][cc], s);
                    s = fmaf(qv[rr][1], mv[1][cc], s);
                    s = fmaf(qv[rr][2], mv[2][cc], s);
                    s = fmaf(qv[rr][3], mv[3][cc], s);
                    S[rr][cc] = s;
                }
        }

        // online softmax update per row (16 lanes share a row group)
#pragma unroll
        for (int rr = 0; rr < 4; ++rr) {
            float mx = fmaxf(fmaxf(S[rr][0], S[rr][1]), fmaxf(S[rr][2], S[rr][3]));
            mx = fmaxf(mx, __shfl_xor(mx, 1));
            mx = fmaxf(mx, __shfl_xor(mx, 2));
            mx = fmaxf(mx, __shfl_xor(mx, 4));
            mx = fmaxf(mx, __shfl_xor(mx, 8));
            float m_new = fmaxf(m_r[rr], mx);
            float scale = __expf(m_r[rr] - m_new);
            float ps = 0.f;
#pragma unroll
            for (int cc = 0; cc < 4; ++cc) {
                float p = __expf(S[rr][cc] - m_new);
                S[rr][cc] = p;
                ps += p;
            }
            ps += __shfl_xor(ps, 1);
            ps += __shfl_xor(ps, 2);
            ps += __shfl_xor(ps, 4);
            ps += __shfl_xor(ps, 8);
            l_r[rr] = l_r[rr] * scale + ps;
            m_r[rr] = m_new;
            O[rr][0] *= scale;
            O[rr][1] *= scale;
            *(float4*)&Pt[ty4 + rr][tx4] = make_float4(S[rr][0], S[rr][1], S[rr][2], S[rr][3]);
        }
        __syncthreads();

        // O += P . M  (rows ty4+rr, feature cols j = tx2+jj)
        for (int c4 = 0; c4 < 64; c4 += 4) {
            float mva[2][4];
            *(float4*)mva[0] = *(const float4*)&Mt[tx2 + 0][c4];
            *(float4*)mva[1] = *(const float4*)&Mt[tx2 + 1][c4];
#pragma unroll
            for (int rr = 0; rr < 4; ++rr) {
                float pv[4];
                *(float4*)pv = *(const float4*)&Pt[ty4 + rr][c4];
#pragma unroll
                for (int jj = 0; jj < 2; ++jj) {
                    float o = O[rr][jj];
                    o = fmaf(pv[0], mva[jj][0], o);
                    o = fmaf(pv[1], mva[jj][1], o);
                    o = fmaf(pv[2], mva[jj][2], o);
                    o = fmaf(pv[3], mva[jj][3], o);
                    O[rr][jj] = o;
                }
            }
        }
    }

    // epilogue: out_pre[b][d][n2*4+a] = O / l
    const int b = pair >> 2;
    const int a = pair & 3;
#pragma unroll
    for (int rr = 0; rr < 4; ++rr) {
        int d = d0 + ty4 + rr;
        float inv = 1.0f / l_r[rr];
#pragma unroll
        for (int jj = 0; jj < 2; ++jj) {
            int n2 = tx2 + jj;
            out_pre[((size_t)(b * SEQ + d)) * 128 + n2 * 4 + a] = O[rr][jj] * inv;
        }
    }
}

// ---------------------------------------------------------------------------
// Kernel 3: y = out_pre @ w_out + b_out
// ---------------------------------------------------------------------------
__global__ __launch_bounds__(256) void out_kernel(const float* __restrict__ out_pre,
                                                  const float* __restrict__ wout,
                                                  const float* __restrict__ bout,
                                                  float* __restrict__ y) {
    __shared__ __align__(16) float xs[8][128];
    const int r0 = blockIdx.x * 8;               // 2048 blocks x 8 rows
    const int t  = threadIdx.x;
    {
        const float4* src = (const float4*)(out_pre + (size_t)r0 * 128);
        ((float4*)&xs[0][0])[t] = src[t];
    }
    __syncthreads();

    const int c  = t & 127;
    const int rh = (t >> 7) * 4;                 // rows rh..rh+3
    float acc[4] = {0.f, 0.f, 0.f, 0.f};

    for (int i = 0; i < 128; i += 4) {
        float w0 = wout[(i + 0) * 128 + c];
        float w1 = wout[(i + 1) * 128 + c];
        float w2 = wout[(i + 2) * 128 + c];
        float w3 = wout[(i + 3) * 128 + c];
#pragma unroll
        for (int p = 0; p < 4; ++p) {
            float4 xp = *(const float4*)&xs[rh + p][i];
            acc[p] = fmaf(xp.x, w0, acc[p]);
            acc[p] = fmaf(xp.y, w1, acc[p]);
            acc[p] = fmaf(xp.z, w2, acc[p]);
            acc[p] = fmaf(xp.w, w3, acc[p]);
        }
    }
    float bb = bout[c];
#pragma unroll
    for (int p = 0; p < 4; ++p) {
        y[((size_t)(r0 + rh + p)) * 128 + c] = acc[p] + bb;
    }
}

// ---------------------------------------------------------------------------
extern "C" void kernel_launch(void* const* d_in, const int* in_sizes, int n_in,
                              void* d_out, int out_size, void* d_ws, size_t ws_size,
                              hipStream_t stream) {
    const float* x    = (const float*)d_in[0];
    const float* wqkv = (const float*)d_in[1];
    const float* wout = (const float*)d_in[2];
    const float* bout = (const float*)d_in[3];
    float* y = (float*)d_out;

    // ws: Qm (8 MB) | MmT (8 MB) | out_pre (8 MB)  -> 24 MB total
    float* Qm      = (float*)d_ws;
    float* MmT     = Qm + (size_t)NPAIR * SEQ * 32;
    float* out_pre = MmT + (size_t)NPAIR * 32 * SEQ;

    kv_kernel<<<1024, 256, 0, stream>>>(x, wqkv, Qm, MmT);
    attn_kernel<<<1024, 256, 0, stream>>>(Qm, MmT, out_pre);
    out_kernel<<<2048, 256, 0, stream>>>(out_pre, wout, bout, y);
}

// Round 2
// 474.056 us; speedup vs baseline: 1.8113x; 1.8113x over previous
//
#include <hip/hip_runtime.h>
#include <math.h>

// x:(4,16,256,128)f32  w_qkv:(128,384)  w_out:(128,128)  b_out:(128)  y:(4,16,256,128)f32
// Reshape map: j=pos>>7, d/e=(pos&127)*32+(c>>2), a=c&3.  Per (b,a) pair:
// flash attn seq=4096 dim=32 with Q=10*l2norm4(k), K=V=M(v).
// ws (24MB): Qhi|Qlo [pair][d][j] bf16, Mhi|Mlo [pair][e][j] bf16,
//            Mpv [pair][j][e~] bf16 (e~ = per-64-block perm (e&15)*4+((e>>4)&3)),
//            outb [row][chan] bf16.

#define SEQ 4096
#define PAIR_ELEMS (SEQ * 32)

typedef __attribute__((ext_vector_type(8))) short bf16x8;
typedef __attribute__((ext_vector_type(4))) float f32x4;

static __device__ __forceinline__ unsigned short f2bf(float x) {
    unsigned u = __float_as_uint(x);
    u += 0x7fffu + ((u >> 16) & 1u);
    return (unsigned short)(u >> 16);
}
static __device__ __forceinline__ float bf2f(unsigned short h) {
    return __uint_as_float(((unsigned)h) << 16);
}

#define PACK_STORE_ROW32(DST, ARR)                                             \
    do {                                                                       \
        unsigned pk_[16];                                                      \
        _Pragma("unroll") for (int k2_ = 0; k2_ < 16; ++k2_)                   \
            pk_[k2_] = (unsigned)(ARR)[2 * k2_] |                              \
                       ((unsigned)(ARR)[2 * k2_ + 1] << 16);                   \
        uint4* d4_ = (uint4*)(DST);                                            \
        d4_[0] = make_uint4(pk_[0], pk_[1], pk_[2], pk_[3]);                   \
        d4_[1] = make_uint4(pk_[4], pk_[5], pk_[6], pk_[7]);                   \
        d4_[2] = make_uint4(pk_[8], pk_[9], pk_[10], pk_[11]);                 \
        d4_[3] = make_uint4(pk_[12], pk_[13], pk_[14], pk_[15]);               \
    } while (0)

// ---------------------------------------------------------------------------
// Kernel 1: k/v GEMM + l2norm + bf16 hi/lo split, fully coalesced row stores.
// Block = (b, p7): 32 x-rows pos = p7 + 128*j (j=0..31). Thread owns one
// channel c (k-half or v-half) -> one full [de][j=0..31] output row.
// ---------------------------------------------------------------------------
__global__ __launch_bounds__(256) void kv_kernel(const float* __restrict__ x,
                                                 const float* __restrict__ wqkv,
                                                 unsigned short* __restrict__ Qhi,
                                                 unsigned short* __restrict__ Qlo,
                                                 unsigned short* __restrict__ Mhi,
                                                 unsigned short* __restrict__ Mlo,
                                                 unsigned short* __restrict__ Mpv) {
    __shared__ unsigned short vstage[32][128];

    const int b    = blockIdx.x >> 7;
    const int p7   = blockIdx.x & 127;
    const int t    = threadIdx.x;
    const int c    = t & 127;
    const int half = t >> 7;                       // 0: k, 1: v
    const int off  = 128 + (half << 7) + c;

    const float* xb = x + ((size_t)(b * SEQ + p7)) * 128;

    float acc[32];
#pragma unroll
    for (int j = 0; j < 32; ++j) acc[j] = 0.f;

    for (int i8 = 0; i8 < 128; i8 += 8) {
        float wv[8];
#pragma unroll
        for (int ii = 0; ii < 8; ++ii) wv[ii] = wqkv[(i8 + ii) * 384 + off];
#pragma unroll
        for (int j = 0; j < 32; ++j) {
            const float* xr = xb + (size_t)j * (128 * 128) + i8;   // uniform addr -> s_load
#pragma unroll
            for (int ii = 0; ii < 8; ++ii) acc[j] = fmaf(xr[ii], wv[ii], acc[j]);
        }
    }

    const int a    = c & 3;
    const int cg   = c >> 2;
    const int pair = (b << 2) + a;
    const int de   = (p7 << 5) + cg;               // row index on d/e axis
    const size_t rowbase = (size_t)pair * PAIR_ELEMS + (size_t)de * 32;

    if (half == 0) {
        unsigned short hi16[32], lo16[32];
#pragma unroll
        for (int j = 0; j < 32; ++j) {
            float v = acc[j];
            float s = v * v;
            s += __shfl_xor(s, 1);
            s += __shfl_xor(s, 2);
            float q = v * 10.0f / fmaxf(sqrtf(s), 1e-12f);
            unsigned short h = f2bf(q);
            hi16[j] = h;
            lo16[j] = f2bf(q - bf2f(h));
        }
        PACK_STORE_ROW32(Qhi + rowbase, hi16);
        PACK_STORE_ROW32(Qlo + rowbase, lo16);
    } else {
        unsigned short hi16[32], lo16[32];
#pragma unroll
        for (int j = 0; j < 32; ++j) {
            float v = acc[j];
            unsigned short h = f2bf(v);
            hi16[j] = h;
            lo16[j] = f2bf(v - bf2f(h));
            vstage[j][c] = h;
        }
        PACK_STORE_ROW32(Mhi + rowbase, hi16);
        PACK_STORE_ROW32(Mlo + rowbase, lo16);
    }
    __syncthreads();

    // Mpv[pair][j][e~]: 2048 packed-u32 tasks; e = 32*p7 + cg ->
    // e~ = (e>>6)*64 + (cg&15)*4 + 2*(p7&1) + (cg>>4); pack (cg=r, cg=r+16).
    unsigned* mpv32 = (unsigned*)Mpv;
#pragma unroll
    for (int u = 0; u < 8; ++u) {
        int task = t + (u << 8);
        int r  = task & 15;
        int jj = (task >> 4) & 31;
        int aa = task >> 9;
        unsigned lo = vstage[jj][(r << 2) + aa];
        unsigned hi = vstage[jj][(r << 2) + aa + 64];
        int pr = (b << 2) + aa;
        size_t dst = (size_t)pr * (PAIR_ELEMS / 2) + (size_t)jj * (SEQ / 2)
                   + ((size_t)(p7 >> 1) << 5) + (r << 1) + (p7 & 1);
        mpv32[dst] = lo | (hi << 16);
    }
}

// ---------------------------------------------------------------------------
// Kernel 2: MFMA flash attention. 512 blocks x 4 independent waves (no
// __syncthreads in main loop). Wave owns 32 d-rows; QK^T = bf16 hi/lo x3
// MFMA; PV = bf16 MFMA; P round-trips wave-private LDS.
// ---------------------------------------------------------------------------
__global__ __launch_bounds__(256) void attn_kernel(const unsigned short* __restrict__ Qhi,
                                                   const unsigned short* __restrict__ Qlo,
                                                   const unsigned short* __restrict__ Mhi,
                                                   const unsigned short* __restrict__ Mlo,
                                                   const unsigned short* __restrict__ Mpv,
                                                   unsigned short* __restrict__ outb) {
    __shared__ __align__(16) unsigned short Plds[4][32][72];  // pad 64->72 (16B-aligned rows)

    const int bid  = blockIdx.x;                 // 512
    const int pair = ((bid & 7) << 1) + (bid >> 8);   // pair -> fixed XCD (bid%8)
    const int dblk = (bid & 255) >> 3;                // 0..31
    const int t    = threadIdx.x;
    const int wid  = t >> 6;
    const int lane = t & 63;
    const int col  = lane & 15;
    const int g    = lane >> 4;
    const int d0   = dblk * 128 + wid * 32;

    const size_t pb = (size_t)pair * PAIR_ELEMS;

    bf16x8 ah[2], al[2];
#pragma unroll
    for (int s = 0; s < 2; ++s) {
        size_t o = pb + (size_t)(d0 + 16 * s + col) * 32 + g * 8;
        ah[s] = *(const bf16x8*)(Qhi + o);
        al[s] = *(const bf16x8*)(Qlo + o);
    }

    f32x4 O[2][2];
    float mrow[2][4], lrow[2][4];
#pragma unroll
    for (int s = 0; s < 2; ++s) {
#pragma unroll
        for (int r = 0; r < 4; ++r) { mrow[s][r] = -1e30f; lrow[s][r] = 0.f; }
#pragma unroll
        for (int nh = 0; nh < 2; ++nh) O[s][nh] = (f32x4){0.f, 0.f, 0.f, 0.f};
    }

    const unsigned short* mh = Mhi + pb;
    const unsigned short* ml = Mlo + pb;
    const unsigned short* mp = Mpv + pb;          // [32 j][4096 e~]
    const f32x4 z = {0.f, 0.f, 0.f, 0.f};

    for (int e0 = 0; e0 < SEQ; e0 += 64) {
        // ---- S = Q*M^T (hi/lo split): S[s][cc], rows d0+16s+4g+r, col e0+16cc+col
        f32x4 S[2][4];
#pragma unroll
        for (int cc = 0; cc < 4; ++cc) {
            size_t ro = (size_t)(e0 + 16 * cc + col) * 32 + g * 8;
            bf16x8 bh = *(const bf16x8*)(mh + ro);
            bf16x8 bl = *(const bf16x8*)(ml + ro);
#pragma unroll
            for (int s = 0; s < 2; ++s) {
                f32x4 tac = __builtin_amdgcn_mfma_f32_16x16x32_bf16(ah[s], bl, z, 0, 0, 0);
                tac = __builtin_amdgcn_mfma_f32_16x16x32_bf16(al[s], bh, tac, 0, 0, 0);
                S[s][cc] = __builtin_amdgcn_mfma_f32_16x16x32_bf16(ah[s], bh, tac, 0, 0, 0);
            }
        }
        // ---- online softmax (row = 4g+r within 16-lane group), P -> LDS (e~ order)
#pragma unroll
        for (int s = 0; s < 2; ++s) {
#pragma unroll
            for (int r = 0; r < 4; ++r) {
                float mx = fmaxf(fmaxf(S[s][0][r], S[s][1][r]), fmaxf(S[s][2][r], S[s][3][r]));
                mx = fmaxf(mx, __shfl_xor(mx, 1));
                mx = fmaxf(mx, __shfl_xor(mx, 2));
                mx = fmaxf(mx, __shfl_xor(mx, 4));
                mx = fmaxf(mx, __shfl_xor(mx, 8));
                float mn  = fmaxf(mrow[s][r], mx);
                float scl = __expf(mrow[s][r] - mn);
                mrow[s][r] = mn;
                float p0 = __expf(S[s][0][r] - mn);
                float p1 = __expf(S[s][1][r] - mn);
                float p2 = __expf(S[s][2][r] - mn);
                float p3 = __expf(S[s][3][r] - mn);
                float ps = p0 + p1 + p2 + p3;
                ps += __shfl_xor(ps, 1);
                ps += __shfl_xor(ps, 2);
                ps += __shfl_xor(ps, 4);
                ps += __shfl_xor(ps, 8);
                lrow[s][r] = lrow[s][r] * scl + ps;
                O[s][0][r] *= scl;
                O[s][1][r] *= scl;
                unsigned w0 = (unsigned)f2bf(p0) | ((unsigned)f2bf(p1) << 16);
                unsigned w1 = (unsigned)f2bf(p2) | ((unsigned)f2bf(p3) << 16);
                unsigned* dst = (unsigned*)&Plds[wid][16 * s + 4 * g + r][col * 4];
                dst[0] = w0;
                dst[1] = w1;
            }
        }
        asm volatile("s_waitcnt lgkmcnt(0)" ::: "memory");
        __builtin_amdgcn_sched_barrier(0);
        // ---- O += P * M  (contraction over e~, B-frags direct from global)
#pragma unroll
        for (int h = 0; h < 2; ++h) {
            bf16x8 pa[2];
#pragma unroll
            for (int s = 0; s < 2; ++s)
                pa[s] = *(const bf16x8*)&Plds[wid][16 * s + col][32 * h + g * 8];
#pragma unroll
            for (int nh = 0; nh < 2; ++nh) {
                bf16x8 bv = *(const bf16x8*)(mp + (size_t)(16 * nh + col) * SEQ
                                             + e0 + 32 * h + g * 8);
                O[0][nh] = __builtin_amdgcn_mfma_f32_16x16x32_bf16(pa[0], bv, O[0][nh], 0, 0, 0);
                O[1][nh] = __builtin_amdgcn_mfma_f32_16x16x32_bf16(pa[1], bv, O[1][nh], 0, 0, 0);
            }
        }
    }

    // ---- epilogue: outb[b][d][n2*4+a] = O/l (bf16)
    const int bb = pair >> 2;
    const int aa = pair & 3;
#pragma unroll
    for (int s = 0; s < 2; ++s) {
#pragma unroll
        for (int r = 0; r < 4; ++r) {
            int d = d0 + 16 * s + 4 * g + r;
            float inv = 1.0f / lrow[s][r];
#pragma unroll
            for (int nh = 0; nh < 2; ++nh) {
                int n2 = 16 * nh + col;
                outb[((size_t)(bb * SEQ + d)) * 128 + n2 * 4 + aa] =
                    f2bf(O[s][nh][r] * inv);
            }
        }
    }
}

// ---------------------------------------------------------------------------
// Kernel 3: y = opre(bf16) @ w_out + b_out  (fp32 vector GEMM)
// ---------------------------------------------------------------------------
__global__ __launch_bounds__(256) void out_kernel(const unsigned short* __restrict__ opre,
                                                  const float* __restrict__ wout,
                                                  const float* __restrict__ bout,
                                                  float* __restrict__ y) {
    __shared__ __align__(16) float xs[8][128];
    const int r0 = blockIdx.x * 8;
    const int t  = threadIdx.x;
    {
        const unsigned* src = (const unsigned*)(opre + (size_t)r0 * 128);
        unsigned v0 = src[t * 2], v1 = src[t * 2 + 1];
        float* dst = &xs[0][0] + t * 4;
        dst[0] = bf2f((unsigned short)(v0 & 0xffff));
        dst[1] = bf2f((unsigned short)(v0 >> 16));
        dst[2] = bf2f((unsigned short)(v1 & 0xffff));
        dst[3] = bf2f((unsigned short)(v1 >> 16));
    }
    __syncthreads();

    const int c  = t & 127;
    const int rh = (t >> 7) * 4;
    float acc[4] = {0.f, 0.f, 0.f, 0.f};

    for (int i = 0; i < 128; i += 4) {
        float w0 = wout[(i + 0) * 128 + c];
        float w1 = wout[(i + 1) * 128 + c];
        float w2 = wout[(i + 2) * 128 + c];
        float w3 = wout[(i + 3) * 128 + c];
#pragma unroll
        for (int p = 0; p < 4; ++p) {
            float4 xp = *(const float4*)&xs[rh + p][i];
            acc[p] = fmaf(xp.x, w0, acc[p]);
            acc[p] = fmaf(xp.y, w1, acc[p]);
            acc[p] = fmaf(xp.z, w2, acc[p]);
            acc[p] = fmaf(xp.w, w3, acc[p]);
        }
    }
    float bb = bout[c];
#pragma unroll
    for (int p = 0; p < 4; ++p) {
        y[((size_t)(r0 + rh + p)) * 128 + c] = acc[p] + bb;
    }
}

// ---------------------------------------------------------------------------
extern "C" void kernel_launch(void* const* d_in, const int* in_sizes, int n_in,
                              void* d_out, int out_size, void* d_ws, size_t ws_size,
                              hipStream_t stream) {
    const float* x    = (const float*)d_in[0];
    const float* wqkv = (const float*)d_in[1];
    const float* wout = (const float*)d_in[2];
    const float* bout = (const float*)d_in[3];
    float* y = (float*)d_out;

    // ws: 6 x 4MB bf16 arrays = 24 MB
    unsigned short* Qhi = (unsigned short*)d_ws;
    unsigned short* Qlo = Qhi + (size_t)16 * PAIR_ELEMS;
    unsigned short* Mhi = Qlo + (size_t)16 * PAIR_ELEMS;
    unsigned short* Mlo = Mhi + (size_t)16 * PAIR_ELEMS;
    unsigned short* Mpv = Mlo + (size_t)16 * PAIR_ELEMS;
    unsigned short* outb = Mpv + (size_t)16 * PAIR_ELEMS;

    kv_kernel<<<512, 256, 0, stream>>>(x, wqkv, Qhi, Qlo, Mhi, Mlo, Mpv);
    attn_kernel<<<512, 256, 0, stream>>>(Qhi, Qlo, Mhi, Mlo, Mpv, outb);
    out_kernel<<<2048, 256, 0, stream>>>(outb, wout, bout, y);
}

// Round 5
// 331.481 us; speedup vs baseline: 2.5903x; 1.4301x over previous
//
#include <hip/hip_runtime.h>
#include <math.h>

// x:(4,16,256,128)f32  w_qkv:(128,384)  w_out:(128,128)  b_out:(128)  y:(4,16,256,128)f32
// Reshape map: J=pos>>7, d/e=(pos&127)*32+(c>>2), a=c&3.  Per (b,a) pair:
// flash attn seq=4096 dim=32, Q=(10*log2e)*l2norm4(k), K=V=M(v), M[e][J]=v.
// Softmax in log2 domain. Exact per-row max from a phase-1 bf16 QK sweep
// (per-lane running max, single end reduce); subtracted for free via the
// MFMA C-operand init in phase 2.  Structure otherwise identical to the
// round-2 kernel that passed the full poisoned-timing protocol.
// ws (24MB): Qhi|Qlo [pair][d][J] bf16, Mhi|Mlo [pair][e][J] bf16,
//            Mpv [pair][J][e~] bf16 (e~ perm within 64-blocks), outb bf16.

#define SEQ 4096
#define PAIR_ELEMS (SEQ * 32)

typedef __attribute__((ext_vector_type(8))) short bf16x8;
typedef __attribute__((ext_vector_type(4))) float f32x4;

static __device__ __forceinline__ unsigned short f2bf(float x) {
    unsigned u = __float_as_uint(x);
    u += 0x7fffu + ((u >> 16) & 1u);
    return (unsigned short)(u >> 16);
}
static __device__ __forceinline__ float bf2f(unsigned short h) {
    return __uint_as_float(((unsigned)h) << 16);
}

#define PACK_STORE_ROW32(DST, ARR)                                             \
    do {                                                                       \
        unsigned pk_[16];                                                      \
        _Pragma("unroll") for (int k2_ = 0; k2_ < 16; ++k2_)                   \
            pk_[k2_] = (unsigned)(ARR)[2 * k2_] |                              \
                       ((unsigned)(ARR)[2 * k2_ + 1] << 16);                   \
        uint4* d4_ = (uint4*)(DST);                                            \
        d4_[0] = make_uint4(pk_[0], pk_[1], pk_[2], pk_[3]);                   \
        d4_[1] = make_uint4(pk_[4], pk_[5], pk_[6], pk_[7]);                   \
        d4_[2] = make_uint4(pk_[8], pk_[9], pk_[10], pk_[11]);                 \
        d4_[3] = make_uint4(pk_[12], pk_[13], pk_[14], pk_[15]);               \
    } while (0)

// ---------------------------------------------------------------------------
// Kernel 1: k/v GEMM + l2norm (log2-scale folded) + bf16 hi/lo split.
// x staged in LDS (round-1/4 style); store paths identical to round 2.
// Block = (b, p7): 32 x-rows pos = p7 + 128*J. Thread owns one channel c.
// ---------------------------------------------------------------------------
__global__ __launch_bounds__(256) void kv_kernel(const float* __restrict__ x,
                                                 const float* __restrict__ wqkv,
                                                 unsigned short* __restrict__ Qhi,
                                                 unsigned short* __restrict__ Qlo,
                                                 unsigned short* __restrict__ Mhi,
                                                 unsigned short* __restrict__ Mlo,
                                                 unsigned short* __restrict__ Mpv) {
    __shared__ __align__(16) float xs[32][128];          // 16 KB
    __shared__ unsigned short vstage[32][128];           // 8 KB

    const int b    = blockIdx.x >> 7;
    const int p7   = blockIdx.x & 127;
    const int t    = threadIdx.x;
    const int c    = t & 127;
    const int half = t >> 7;                       // 0: k, 1: v
    const int off  = 128 + (half << 7) + c;

    // stage x rows (coalesced float4)
    {
        const float* xb = x + ((size_t)(b * SEQ + p7)) * 128;
#pragma unroll
        for (int u = 0; u < 4; ++u) {
            int idx = t + (u << 8);                // 0..1023
            int j   = idx >> 5;
            int c4  = idx & 31;
            *(float4*)&xs[j][c4 * 4] =
                *(const float4*)(xb + (size_t)j * (128 * 128) + c4 * 4);
        }
    }
    __syncthreads();

    float acc[32];
#pragma unroll
    for (int j = 0; j < 32; ++j) acc[j] = 0.f;

    for (int i8 = 0; i8 < 128; i8 += 8) {
        float wv[8];
#pragma unroll
        for (int ii = 0; ii < 8; ++ii) wv[ii] = wqkv[(i8 + ii) * 384 + off];
#pragma unroll
        for (int j = 0; j < 32; ++j) {
            float4 xa  = *(const float4*)&xs[j][i8];
            float4 xb4 = *(const float4*)&xs[j][i8 + 4];
            acc[j] = fmaf(xa.x, wv[0], acc[j]);
            acc[j] = fmaf(xa.y, wv[1], acc[j]);
            acc[j] = fmaf(xa.z, wv[2], acc[j]);
            acc[j] = fmaf(xa.w, wv[3], acc[j]);
            acc[j] = fmaf(xb4.x, wv[4], acc[j]);
            acc[j] = fmaf(xb4.y, wv[5], acc[j]);
            acc[j] = fmaf(xb4.z, wv[6], acc[j]);
            acc[j] = fmaf(xb4.w, wv[7], acc[j]);
        }
    }

    const int a    = c & 3;
    const int cg   = c >> 2;
    const int pair = (b << 2) + a;
    const int de   = (p7 << 5) + cg;
    const size_t rowbase = (size_t)pair * PAIR_ELEMS + (size_t)de * 32;

    if (half == 0) {
        // Q = (10*log2e) * l2norm4(k): log2-domain scale folded in
        unsigned short hi16[32], lo16[32];
#pragma unroll
        for (int j = 0; j < 32; ++j) {
            float v = acc[j];
            float s = v * v;
            s += __shfl_xor(s, 1);
            s += __shfl_xor(s, 2);
            float q = v * 14.426950408889634f / fmaxf(sqrtf(s), 1e-12f);
            unsigned short h = f2bf(q);
            hi16[j] = h;
            lo16[j] = f2bf(q - bf2f(h));
        }
        PACK_STORE_ROW32(Qhi + rowbase, hi16);
        PACK_STORE_ROW32(Qlo + rowbase, lo16);
    } else {
        unsigned short hi16[32], lo16[32];
#pragma unroll
        for (int j = 0; j < 32; ++j) {
            float v = acc[j];
            unsigned short h = f2bf(v);
            hi16[j] = h;
            lo16[j] = f2bf(v - bf2f(h));
            vstage[j][c] = h;
        }
        PACK_STORE_ROW32(Mhi + rowbase, hi16);
        PACK_STORE_ROW32(Mlo + rowbase, lo16);
    }
    __syncthreads();

    // Mpv[pair][J][e~] scatter — identical to the round-2 passing kernel.
    unsigned* mpv32 = (unsigned*)Mpv;
#pragma unroll
    for (int u = 0; u < 8; ++u) {
        int task = t + (u << 8);                   // 2048 tasks
        int r  = task & 15;
        int jj = (task >> 4) & 31;
        int aa = task >> 9;
        unsigned lo = vstage[jj][(r << 2) + aa];
        unsigned hi = vstage[jj][(r << 2) + aa + 64];
        int pr = (b << 2) + aa;
        size_t dst = (size_t)pr * (PAIR_ELEMS / 2) + (size_t)jj * (SEQ / 2)
                   + ((size_t)(p7 >> 1) << 5) + (r << 1) + (p7 & 1);
        mpv32[dst] = lo | (hi << 16);
    }
}

// ---------------------------------------------------------------------------
// Kernel 2: MFMA flash attention — round-2 structure (512 blocks x 4 waves x
// 32 d-rows, Plds[4][32][72], flat Mpv B-loads) + phase-1/phase-2 softmax:
//   phase 1: bf16 QK sweep -> exact per-row max (per-lane, one end reduce)
//   phase 2: hi/lo QK with C-init = -max, P=exp2(S), per-lane l partials.
// ---------------------------------------------------------------------------
__global__ __launch_bounds__(256) void attn_kernel(const unsigned short* __restrict__ Qhi,
                                                   const unsigned short* __restrict__ Qlo,
                                                   const unsigned short* __restrict__ Mhi,
                                                   const unsigned short* __restrict__ Mlo,
                                                   const unsigned short* __restrict__ Mpv,
                                                   unsigned short* __restrict__ outb) {
    __shared__ __align__(16) unsigned short Plds[4][32][72];  // 18 KB

    const int bid  = blockIdx.x;                 // 512
    const int pair = ((bid & 7) << 1) + (bid >> 8);   // pair -> fixed XCD
    const int dblk = (bid & 255) >> 3;                // 0..31
    const int t    = threadIdx.x;
    const int wid  = t >> 6;
    const int lane = t & 63;
    const int col  = lane & 15;
    const int g    = lane >> 4;
    const int d0   = dblk * 128 + wid * 32;

    const size_t pb = (size_t)pair * PAIR_ELEMS;

    bf16x8 ah[2], al[2];
#pragma unroll
    for (int s = 0; s < 2; ++s) {
        size_t o = pb + (size_t)(d0 + 16 * s + col) * 32 + g * 8;
        ah[s] = *(const bf16x8*)(Qhi + o);
        al[s] = *(const bf16x8*)(Qlo + o);
    }

    const unsigned short* mh = Mhi + pb;
    const unsigned short* ml = Mlo + pb;
    const unsigned short* mp = Mpv + pb;          // [32 J][4096 e~]
    const f32x4 z = {0.f, 0.f, 0.f, 0.f};

    // ---- phase 1: exact row max of bf16 QK (no cross-lane in loop)
    float rmax[2][4];
#pragma unroll
    for (int s = 0; s < 2; ++s)
#pragma unroll
        for (int r = 0; r < 4; ++r) rmax[s][r] = -3e38f;

    for (int e0 = 0; e0 < SEQ; e0 += 64) {
#pragma unroll
        for (int cc = 0; cc < 4; ++cc) {
            size_t ro = (size_t)(e0 + 16 * cc + col) * 32 + g * 8;
            bf16x8 bh = *(const bf16x8*)(mh + ro);
#pragma unroll
            for (int s = 0; s < 2; ++s) {
                f32x4 sv = __builtin_amdgcn_mfma_f32_16x16x32_bf16(ah[s], bh, z, 0, 0, 0);
#pragma unroll
                for (int r = 0; r < 4; ++r) rmax[s][r] = fmaxf(rmax[s][r], sv[r]);
            }
        }
    }
#pragma unroll
    for (int s = 0; s < 2; ++s)
#pragma unroll
        for (int r = 0; r < 4; ++r) {
            float m = rmax[s][r];
            m = fmaxf(m, __shfl_xor(m, 1));
            m = fmaxf(m, __shfl_xor(m, 2));
            m = fmaxf(m, __shfl_xor(m, 4));
            m = fmaxf(m, __shfl_xor(m, 8));
            rmax[s][r] = m;
        }
    f32x4 minit[2];
#pragma unroll
    for (int s = 0; s < 2; ++s)
        minit[s] = (f32x4){-rmax[s][0], -rmax[s][1], -rmax[s][2], -rmax[s][3]};

    f32x4 O[2][2];
    float lsum[2][4];
#pragma unroll
    for (int s = 0; s < 2; ++s) {
#pragma unroll
        for (int r = 0; r < 4; ++r) lsum[s][r] = 0.f;
#pragma unroll
        for (int nh = 0; nh < 2; ++nh) O[s][nh] = (f32x4){0.f, 0.f, 0.f, 0.f};
    }

    // ---- phase 2: main flash loop (structure = round-2 passing kernel)
    for (int e0 = 0; e0 < SEQ; e0 += 64) {
        f32x4 S[2][4];
#pragma unroll
        for (int cc = 0; cc < 4; ++cc) {
            size_t ro = (size_t)(e0 + 16 * cc + col) * 32 + g * 8;
            bf16x8 bh = *(const bf16x8*)(mh + ro);
            bf16x8 bl = *(const bf16x8*)(ml + ro);
#pragma unroll
            for (int s = 0; s < 2; ++s) {
                f32x4 tac = __builtin_amdgcn_mfma_f32_16x16x32_bf16(ah[s], bl, minit[s], 0, 0, 0);
                tac = __builtin_amdgcn_mfma_f32_16x16x32_bf16(al[s], bh, tac, 0, 0, 0);
                S[s][cc] = __builtin_amdgcn_mfma_f32_16x16x32_bf16(ah[s], bh, tac, 0, 0, 0);
            }
        }
        // P = exp2(S), per-lane l partials, P -> LDS (bf16, round-2 packing)
#pragma unroll
        for (int s = 0; s < 2; ++s) {
#pragma unroll
            for (int r = 0; r < 4; ++r) {
                float p0 = __builtin_amdgcn_exp2f(S[s][0][r]);
                float p1 = __builtin_amdgcn_exp2f(S[s][1][r]);
                float p2 = __builtin_amdgcn_exp2f(S[s][2][r]);
                float p3 = __builtin_amdgcn_exp2f(S[s][3][r]);
                lsum[s][r] += (p0 + p1) + (p2 + p3);
                unsigned w0 = (unsigned)f2bf(p0) | ((unsigned)f2bf(p1) << 16);
                unsigned w1 = (unsigned)f2bf(p2) | ((unsigned)f2bf(p3) << 16);
                unsigned* dst = (unsigned*)&Plds[wid][16 * s + 4 * g + r][col * 4];
                dst[0] = w0;
                dst[1] = w1;
            }
        }
        asm volatile("s_waitcnt lgkmcnt(0)" ::: "memory");
        __builtin_amdgcn_sched_barrier(0);
        // O += P * M  (B-frags direct from global, flat Mpv — round-2 exact)
#pragma unroll
        for (int h = 0; h < 2; ++h) {
            bf16x8 pa[2];
#pragma unroll
            for (int s = 0; s < 2; ++s)
                pa[s] = *(const bf16x8*)&Plds[wid][16 * s + col][32 * h + g * 8];
#pragma unroll
            for (int nh = 0; nh < 2; ++nh) {
                bf16x8 bv = *(const bf16x8*)(mp + (size_t)(16 * nh + col) * SEQ
                                             + e0 + 32 * h + g * 8);
                O[0][nh] = __builtin_amdgcn_mfma_f32_16x16x32_bf16(pa[0], bv, O[0][nh], 0, 0, 0);
                O[1][nh] = __builtin_amdgcn_mfma_f32_16x16x32_bf16(pa[1], bv, O[1][nh], 0, 0, 0);
            }
        }
        // keep program order: this iter's Plds reads before next iter's writes
        asm volatile("" ::: "memory");
    }

    // ---- final l reduce across the 16 col-lanes
#pragma unroll
    for (int s = 0; s < 2; ++s)
#pragma unroll
        for (int r = 0; r < 4; ++r) {
            float l = lsum[s][r];
            l += __shfl_xor(l, 1);
            l += __shfl_xor(l, 2);
            l += __shfl_xor(l, 4);
            l += __shfl_xor(l, 8);
            lsum[s][r] = l;
        }

    // ---- epilogue: outb[b][d][n2*4+a] = O/l (bf16) — round-2 exact
    const int bb = pair >> 2;
    const int aa = pair & 3;
#pragma unroll
    for (int s = 0; s < 2; ++s) {
#pragma unroll
        for (int r = 0; r < 4; ++r) {
            int d = d0 + 16 * s + 4 * g + r;
            float inv = 1.0f / lsum[s][r];
#pragma unroll
            for (int nh = 0; nh < 2; ++nh) {
                int n2 = 16 * nh + col;
                outb[((size_t)(bb * SEQ + d)) * 128 + n2 * 4 + aa] =
                    f2bf(O[s][nh][r] * inv);
            }
        }
    }
}

// ---------------------------------------------------------------------------
// Kernel 3: y = opre(bf16) @ w_out + b_out  (fp32 vector GEMM) — round-2 exact
// ---------------------------------------------------------------------------
__global__ __launch_bounds__(256) void out_kernel(const unsigned short* __restrict__ opre,
                                                  const float* __restrict__ wout,
                                                  const float* __restrict__ bout,
                                                  float* __restrict__ y) {
    __shared__ __align__(16) float xs[8][128];
    const int r0 = blockIdx.x * 8;
    const int t  = threadIdx.x;
    {
        const unsigned* src = (const unsigned*)(opre + (size_t)r0 * 128);
        unsigned v0 = src[t * 2], v1 = src[t * 2 + 1];
        float* dst = &xs[0][0] + t * 4;
        dst[0] = bf2f((unsigned short)(v0 & 0xffff));
        dst[1] = bf2f((unsigned short)(v0 >> 16));
        dst[2] = bf2f((unsigned short)(v1 & 0xffff));
        dst[3] = bf2f((unsigned short)(v1 >> 16));
    }
    __syncthreads();

    const int c  = t & 127;
    const int rh = (t >> 7) * 4;
    float acc[4] = {0.f, 0.f, 0.f, 0.f};

    for (int i = 0; i < 128; i += 4) {
        float w0 = wout[(i + 0) * 128 + c];
        float w1 = wout[(i + 1) * 128 + c];
        float w2 = wout[(i + 2) * 128 + c];
        float w3 = wout[(i + 3) * 128 + c];
#pragma unroll
        for (int p = 0; p < 4; ++p) {
            float4 xp = *(const float4*)&xs[rh + p][i];
            acc[p] = fmaf(xp.x, w0, acc[p]);
            acc[p] = fmaf(xp.y, w1, acc[p]);
            acc[p] = fmaf(xp.z, w2, acc[p]);
            acc[p] = fmaf(xp.w, w3, acc[p]);
        }
    }
    float bb = bout[c];
#pragma unroll
    for (int p = 0; p < 4; ++p) {
        y[((size_t)(r0 + rh + p)) * 128 + c] = acc[p] + bb;
    }
}

// ---------------------------------------------------------------------------
extern "C" void kernel_launch(void* const* d_in, const int* in_sizes, int n_in,
                              void* d_out, int out_size, void* d_ws, size_t ws_size,
                              hipStream_t stream) {
    const float* x    = (const float*)d_in[0];
    const float* wqkv = (const float*)d_in[1];
    const float* wout = (const float*)d_in[2];
    const float* bout = (const float*)d_in[3];
    float* y = (float*)d_out;

    unsigned short* Qhi = (unsigned short*)d_ws;
    unsigned short* Qlo = Qhi + (size_t)16 * PAIR_ELEMS;
    unsigned short* Mhi = Qlo + (size_t)16 * PAIR_ELEMS;
    unsigned short* Mlo = Mhi + (size_t)16 * PAIR_ELEMS;
    unsigned short* Mpv = Mlo + (size_t)16 * PAIR_ELEMS;
    unsigned short* outb = Mpv + (size_t)16 * PAIR_ELEMS;

    kv_kernel<<<512, 256, 0, stream>>>(x, wqkv, Qhi, Qlo, Mhi, Mlo, Mpv);
    attn_kernel<<<512, 256, 0, stream>>>(Qhi, Qlo, Mhi, Mlo, Mpv, outb);
    out_kernel<<<2048, 256, 0, stream>>>(outb, wout, bout, y);
}